// Round 2
// baseline (821.942 us; speedup 1.0000x reference)
//
#include <hip/hip_runtime.h>
#include <hip/hip_bf16.h>

// out = relu((x * drop_mask) @ weight @ support)
// Fused via associativity: W = weight @ support (128x128, precomputed per launch),
// then out = relu(xd @ W) -- a single memory-bound N=500k GEMM with K=N_out=128.
//
// R2: software-pipelined prefetch (loads for slab s+1 issued before MFMA of s),
// transposed MFMA operand order -> each lane stores contiguous float4 rows,
// fragment-ordered conflict-free LDS layout for W (32 KB, no padding).

#define D 128

typedef __attribute__((ext_vector_type(8))) short short8;
typedef __attribute__((ext_vector_type(4))) float f32x4;

__device__ __forceinline__ short f2bf(float f) {
    union { __hip_bfloat16 h; short s; } u;
    u.h = __float2bfloat16(f);
    return u.s;
}

// --- Kernel 1: Wt[n][k] = (weight @ support)[k][n], bf16, into d_ws ---
__global__ void wprod_kernel(const float* __restrict__ weight,
                             const float* __restrict__ support,
                             unsigned short* __restrict__ wt) {
    __shared__ float wrow[D];
    const int i = blockIdx.x;
    const int j = threadIdx.x;
    wrow[j] = weight[i * D + j];
    __syncthreads();
    float acc = 0.f;
#pragma unroll 8
    for (int k = 0; k < D; ++k)
        acc = fmaf(wrow[k], support[k * D + j], acc);
    union { __hip_bfloat16 h; unsigned short s; } u;
    u.h = __float2bfloat16(acc);
    wt[(size_t)j * D + i] = u.s;  // transposed: row n holds W[.][n] over k
}

// --- Kernel 2: out = relu(xd @ W) ---
__global__ __launch_bounds__(256, 4) void gcn_fused(
    const float* __restrict__ x, const float* __restrict__ mask,
    const unsigned short* __restrict__ wt, float* __restrict__ out,
    int nslabs) {
    // Fragment-ordered W: entry [ (n*4+kk)*64 + lane ] is the 8-short B-fragment
    // Wt[n*16+m][kk*32 + q*8 ...], lane = q*16+m. Lane-sequential 16B reads ->
    // conflict-free, no padding. 16384 shorts = 32 KB.
    __shared__ __align__(16) unsigned short lw[8 * 4 * 64 * 8];

    {
        const uint4* src = reinterpret_cast<const uint4*>(wt);
        uint4* dst = reinterpret_cast<uint4*>(lw);
        for (int f = threadIdx.x; f < 2048; f += 256) {
            const int n = f >> 8;
            const int kk = (f >> 6) & 3;
            const int l = f & 63;
            const int q = l >> 4, m = l & 15;
            dst[f] = src[((n * 16 + m) * D + kk * 32 + q * 8) >> 3];
        }
    }
    __syncthreads();

    const int lane = threadIdx.x & 63;
    const int m = lane & 15;    // x-row within slab / output row
    const int q = lane >> 4;    // k-subchunk selector / output col quad

    const int wave = (blockIdx.x * blockDim.x + threadIdx.x) >> 6;
    const int nwaves = (gridDim.x * blockDim.x) >> 6;

    const short8* bfr = reinterpret_cast<const short8*>(lw) + lane;

    f32x4 xv[8], mv[8];

#define ISSUE_LOADS(ss)                                                        \
    do {                                                                       \
        const float* xr_ = x + ((size_t)(ss) * 16 + m) * D + q * 8;            \
        const float* mr_ = mask + ((size_t)(ss) * 16 + m) * D + q * 8;         \
        _Pragma("unroll") for (int kk = 0; kk < 4; ++kk) {                     \
            xv[kk * 2]     = *reinterpret_cast<const f32x4*>(xr_ + kk * 32);   \
            xv[kk * 2 + 1] = *reinterpret_cast<const f32x4*>(xr_ + kk * 32 + 4);\
            mv[kk * 2]     = *reinterpret_cast<const f32x4*>(mr_ + kk * 32);   \
            mv[kk * 2 + 1] = *reinterpret_cast<const f32x4*>(mr_ + kk * 32 + 4);\
        }                                                                      \
    } while (0)

    int s = wave;
    if (s < nslabs) ISSUE_LOADS(s);

    for (; s < nslabs; s += nwaves) {
        // consume prefetched loads -> bf16 A fragments (this is where vmcnt waits)
        short8 a[4];
#pragma unroll
        for (int kk = 0; kk < 4; ++kk) {
            const f32x4 p0 = xv[kk * 2] * mv[kk * 2];
            const f32x4 p1 = xv[kk * 2 + 1] * mv[kk * 2 + 1];
            short8 v;
            v[0] = f2bf(p0[0]); v[1] = f2bf(p0[1]);
            v[2] = f2bf(p0[2]); v[3] = f2bf(p0[3]);
            v[4] = f2bf(p1[0]); v[5] = f2bf(p1[1]);
            v[6] = f2bf(p1[2]); v[7] = f2bf(p1[3]);
            a[kk] = v;
        }

        // issue next slab's loads NOW -- they fly during MFMA + stores below
        const int s2 = s + nwaves;
        if (s2 < nslabs) ISSUE_LOADS(s2);

        // W-fragment as FIRST operand: D[i][j] = sum_k W[k][n*16+i] * x[j][k]
        // C/D layout (row=q*4+r, col=lane&15) => lane holds out[row m][cols
        // n*16 + q*4 .. +3] -- a contiguous float4 per n-tile.
        float* orow = out + ((size_t)s * 16 + m) * D + q * 4;
#pragma unroll
        for (int n = 0; n < 8; ++n) {
            f32x4 acc = {0.f, 0.f, 0.f, 0.f};
#pragma unroll
            for (int kk = 0; kk < 4; ++kk)
                acc = __builtin_amdgcn_mfma_f32_16x16x32_bf16(
                    bfr[(n * 4 + kk) * 64], a[kk], acc, 0, 0, 0);
            f32x4 r;
            r[0] = fmaxf(acc[0], 0.f);
            r[1] = fmaxf(acc[1], 0.f);
            r[2] = fmaxf(acc[2], 0.f);
            r[3] = fmaxf(acc[3], 0.f);
            *reinterpret_cast<f32x4*>(orow + n * 16) = r;
        }
    }
#undef ISSUE_LOADS
}

extern "C" void kernel_launch(void* const* d_in, const int* in_sizes, int n_in,
                              void* d_out, int out_size, void* d_ws, size_t ws_size,
                              hipStream_t stream) {
    const float* x = (const float*)d_in[0];
    const float* weight = (const float*)d_in[1];
    const float* support = (const float*)d_in[2];
    const float* mask = (const float*)d_in[3];
    float* out = (float*)d_out;
    unsigned short* wt = (unsigned short*)d_ws;  // 128*128 bf16 = 32 KB

    const int nrows = in_sizes[0] / D;   // 500000
    const int nslabs = nrows / 16;       // 31250 (exact)

    wprod_kernel<<<dim3(D), dim3(D), 0, stream>>>(weight, support, wt);
    gcn_fused<<<dim3(2048), dim3(256), 0, stream>>>(x, mask, wt, out, nslabs);
}